// Round 11
// baseline (647.806 us; speedup 1.0000x reference)
//
#include <hip/hip_runtime.h>
#include <math.h>

#define HH 384
#define WW 384
#define NPIX (HH*WW)          // 147456
#define NB 2
#define BN (NB*NPIX)          // 294912
#define NT 128
#define NBINS 32
#define MEDRANK ((NPIX-1)/2)  // 73727
#define RB 72
#define RB2 288
#define SEL_BLK 64
#define KDG 8
#define KSEG 16
#define GHS 496   // Hh half stride (=480+16; ≡16 mod 32 -> 2-way max on phase2 reads)
#define GVS 272   // Vv stride (=256+16)

// ---- double arena (ws+0, 2048 doubles) ----
#define A_BETA 0
#define A_XZ   16
#define A_ES   40
#define A_DK   56
#define A_GMM  128  // it*8 + b*4 + {N0,Sx0,Sxx0}
#define A_ZTOT 272
#define A_GHIST 288
#define A_KURT 512

// ---- float arena (ws+16384, 4096 floats) ----
#define F_BETA 0
#define F_X3   8
#define F_MEAN 24
#define F_WWH  32
#define F_ASTAR 828
#define F_ZBQ  868
#define F_DKINV 880
#define F_CM   918   // 8 med/mad pairs: (kk*4+isG*2+b)*2
#define F_ESI  940
#define F_LAQ  952
#define F_GCDF 968
#define F_MMS_MIN 1280
#define F_MMS_MAX 1408

__device__ __forceinline__ double waveSum(double v){
#pragma unroll
  for(int o=32;o;o>>=1) v += __shfl_down(v,o,64);
  return v;
}
__device__ __forceinline__ unsigned f2u(float f){
  unsigned u = __float_as_uint(f);
  return (u & 0x80000000u) ? ~u : (u | 0x80000000u);
}
__device__ __forceinline__ float u2f(unsigned u){
  return __uint_as_float((u & 0x80000000u) ? (u ^ 0x80000000u) : ~u);
}
__device__ __forceinline__ float sp(float x){
  float t = log1pf(expf(-fabsf(x)));
  return x >= 0.f ? x + t : t;
}

struct SelBatch {
  const float* src[8];
  int rank[8];
  int fslot[8];
  int nt;
  int medmad;
};

__device__ void pickN(const unsigned* hp, int nb, int rank, unsigned& sel, int& nrank){
  __shared__ unsigned s_cum[256];
  __shared__ unsigned s_res[2];
  int tid = threadIdx.x;
  int base = tid*8;
  unsigned loc[8]; unsigned tsum=0;
#pragma unroll
  for(int j=0;j<8;j++){ unsigned v=(base+j<nb)?hp[base+j]:0u; loc[j]=v; tsum+=v; }
  s_cum[tid]=tsum;
  __syncthreads();
  for(int o=1;o<256;o<<=1){
    unsigned t=(tid>=o)?s_cum[tid-o]:0u;
    __syncthreads();
    s_cum[tid]+=t;
    __syncthreads();
  }
  unsigned cum=s_cum[tid], ex=cum-tsum;
  if(tsum>0u && (unsigned)rank>=ex && (unsigned)rank<cum){
    int rr=rank-(int)ex; unsigned bsel=0;
#pragma unroll
    for(int j=0;j<8;j++){ if((unsigned)rr<loc[j]){ bsel=(unsigned)(base+j); break; } rr-=(int)loc[j]; }
    s_res[0]=bsel; s_res[1]=(unsigned)rr;
  }
  __syncthreads();
  sel=s_res[0]; nrank=(int)s_res[1];
  __syncthreads();
}

__global__ void k_zero(double* A, float* F, unsigned* T, unsigned* H){
  int i = blockIdx.x*256 + threadIdx.x;
  if(i < 2048) A[i] = 0.0;
  if(i < 4096){
    unsigned* U = (unsigned*)F;
    unsigned v = 0u;
    if(i>=F_MMS_MIN && i<F_MMS_MIN+64) v = 0xFFFFFFFFu;
    U[i] = v;
  }
  if(i < 512) T[i] = 0u;
  for(int j=i; j<240*2048; j+=65536) H[j]=0u;
}

// 11/11/10-bit radix pass
__global__ __launch_bounds__(256) void k_selp(SelBatch sb, unsigned* Hh, unsigned* T,
                                              float* F, int bid, int stage, int p){
  int task = blockIdx.x / SEL_BLK;
  int blk  = blockIdx.x % SEL_BLK;
  unsigned* meta = T + 384 + task*8;
  float center = (stage==1) ? __uint_as_float(meta[4]) : 0.f;
  unsigned pre = (p==2) ? 0u : meta[stage*2];
  __shared__ unsigned lh[2048];
  for(int j=threadIdx.x;j<2048;j+=256) lh[j]=0u;
  __syncthreads();
  const float* src = sb.src[task];
  for(int i=blk*256+threadIdx.x; i<NPIX; i+=SEL_BLK*256){
    float v = src[i];
    if(stage) v = fabsf(v-center);
    unsigned u = f2u(v);
    unsigned bin; bool ok;
    if(p==2){ bin = u>>21; ok = true; }
    else if(p==1){ bin = (u>>10)&2047u; ok = ((u>>21)==pre); }
    else { bin = u&1023u; ok = ((u>>10)==pre); }
    if(ok) atomicAdd(&lh[bin],1u);
  }
  __syncthreads();
  unsigned* hp = Hh + (size_t)(((bid*8+task)*2+stage)*3 + (2-p))*2048;
  for(int j=threadIdx.x;j<2048;j+=256){ unsigned c=lh[j]; if(c) atomicAdd(hp+j,c); }
  __shared__ int s_last;
  __syncthreads();
  if(threadIdx.x==0){
    __threadfence();
    s_last = (atomicAdd(&T[16+bid*64+task*8+stage*4+(2-p)],1u) == (unsigned)(SEL_BLK-1));
  }
  __syncthreads();
  if(!s_last) return;
  int r = (p==2) ? sb.rank[task] : (int)meta[stage*2+1];
  int nb = (p==0) ? 1024 : 2048;
  unsigned sel; int nr;
  pickN(hp, nb, r, sel, nr);
  if(threadIdx.x==0){
    if(p==2){ meta[stage*2]=sel; meta[stage*2+1]=(unsigned)nr; }
    else if(p==1){ meta[stage*2]=(pre<<11)|sel; meta[stage*2+1]=(unsigned)nr; }
    else {
      float val = u2f((pre<<10)|sel);
      if(stage==0){
        if(sb.medmad) meta[4]=__float_as_uint(val);
        else F[sb.fslot[task]]=val;
      } else {
        F[sb.fslot[task]]   = __uint_as_float(meta[4]);
        F[sb.fslot[task]+1] = val*1.4826f + 1e-8f;
      }
    }
  }
}

__device__ void quad_from_stats(double N0,double Sx0,double Sxx0,double Sxt,double Sxxt,
                                float& qa,float& qb,float& qc){
  double Nt=(double)NPIX;
  double N1=Nt-N0, Sx1=Sxt-Sx0, Sxx1=Sxxt-Sxx0;
  double mu0=Sx0/(N0+1e-8), mu1=Sx1/(N1+1e-8);
  double v0=(Sxx0-2.0*mu0*Sx0+mu0*mu0*N0)/(N0+1e-8)+1e-6;
  double v1=(Sxx1-2.0*mu1*Sx1+mu1*mu1*N1)/(N1+1e-8)+1e-6;
  double p0=N0/Nt, p1=N1/Nt;
  double c0=-0.5*log(v0+1e-6)+log(p0+1e-8);
  double c1=-0.5*log(v1+1e-6)+log(p1+1e-8);
  double iv0=0.5/(v0+1e-6), iv1=0.5/(v1+1e-6);
  qa=(float)(iv0-iv1);
  qb=(float)(2.0*(iv1*mu1-iv0*mu0));
  qc=(float)(iv0*mu0*mu0-iv1*mu1*mu1+c1-c0);
}
__device__ void quad_init(const float* F,int b,float& qa,float& qb,float& qc){
  const float* z = F + F_ZBQ + b*4;
  double h25 = 0.25*(double)(NPIX-1); double f25 = h25 - floor(h25);
  double h75 = 0.75*(double)(NPIX-1); double f75 = h75 - floor(h75);
  double mu0 = (double)z[0] + f25*((double)z[1]-(double)z[0]);
  double mu1 = (double)z[2] + f75*((double)z[3]-(double)z[2]);
  double iv = 0.5/(1.0+1e-6);
  qa = 0.f;
  qb = (float)(2.0*iv*(mu1-mu0));
  qc = (float)(iv*(mu0*mu0-mu1*mu1));
}

// ---------------- pipeline kernels ----------------
__global__ __launch_bounds__(256) void k_sobel(const float* lab, float* S, float* E){
  int bx = blockIdx.x % 24, by = (blockIdx.x/24) % 24, b = blockIdx.x/576;
  __shared__ float Lt[20][21];
  __shared__ float G[18][19];
  const float* Lb = lab + b*3*NPIX;
  int ox = bx*16, oy = by*16;
  for(int i=threadIdx.x; i<400; i+=256){
    int lx=i%20, ly=i/20;
    int gx_=ox-2+lx, gy_=oy-2+ly;
    Lt[ly][lx] = (gx_<0||gx_>=WW||gy_<0||gy_>=HH)?0.f:Lb[gy_*WW+gx_];
  }
  __syncthreads();
  for(int i=threadIdx.x; i<324; i+=256){
    int lx=i%18, ly=i/18;
    int px=lx+1, py=ly+1;
    int gxp=ox-2+px, gyp=oy-2+py;
    float g=0.f;
    if(gxp>=0&&gxp<WW&&gyp>=0&&gyp<HH){
      float gx = -Lt[py-1][px-1]+Lt[py-1][px+1] -2.f*Lt[py][px-1]+2.f*Lt[py][px+1] -Lt[py+1][px-1]+Lt[py+1][px+1];
      float gy = -Lt[py-1][px-1]-2.f*Lt[py-1][px]-Lt[py-1][px+1] +Lt[py+1][px-1]+2.f*Lt[py+1][px]+Lt[py+1][px+1];
      g = gx*gx+gy*gy;
    }
    G[ly][lx]=g;
  }
  __syncthreads();
  int tx = threadIdx.x%16, ty = threadIdx.x/16;
  float s=0;
#pragma unroll
  for(int dy=0;dy<3;dy++)
#pragma unroll
    for(int dx=0;dx<3;dx++) s += G[ty+dy][tx+dx];
  int n = (oy+ty)*WW + ox+tx;
  E[b*NPIX+n] = s*(1.f/9.f);
  float av=Lb[NPIX+n], bv=Lb[2*NPIX+n];
  S[b*NPIX+n] = sqrtf(av*av+bv*bv+1e-8f);
}

__global__ void k_beta_red(const float* E,const float* S,const float* lab,double* A,
                           float* F, unsigned* T){
  int b = blockIdx.x / RB, blk = blockIdx.x % RB;
  double s[5]={0,0,0,0,0};
  for(int n = blk*256 + threadIdx.x; n < NPIX; n += RB*256){
    float e=E[b*NPIX+n], ss=S[b*NPIX+n], l=lab[b*3*NPIX+n];
    s[0]+=(double)e*e; s[1]+=(double)e*ss; s[2]+=(double)ss*ss;
    s[3]+=(double)e*l; s[4]+=(double)ss*l;
  }
  __shared__ double red[4][5];
  int wave=threadIdx.x>>6, lane=threadIdx.x&63;
#pragma unroll
  for(int q=0;q<5;q++){
    s[q]=waveSum(s[q]);
    if(lane==0) red[wave][q]=s[q];
  }
  __syncthreads();
  if(threadIdx.x<5){
    double v = red[0][threadIdx.x]+red[1][threadIdx.x]+red[2][threadIdx.x]+red[3][threadIdx.x];
    atomicAdd(&A[A_BETA+b*5+threadIdx.x], v);
  }
  __shared__ int s_last;
  __syncthreads();
  if(threadIdx.x==0){
    __threadfence();
    s_last = (atomicAdd(&T[0],1u) == (unsigned)(NB*RB-1));
  }
  __syncthreads();
  if(!s_last || threadIdx.x) return;
  for(int bb=0;bb<NB;bb++){
    double EE=A[A_BETA+bb*5],ES=A[A_BETA+bb*5+1],SS=A[A_BETA+bb*5+2],EL=A[A_BETA+bb*5+3],SL=A[A_BETA+bb*5+4];
    double a00=EE+1e-6, a01=ES, a11=SS+1e-6;
    double det=a00*a11-a01*a01;
    F[F_BETA+bb*2]  =(float)(( a11*EL - a01*SL)/det);
    F[F_BETA+bb*2+1]=(float)((-a01*EL + a00*SL)/det);
  }
}

__global__ void k_lperp(const float* lab,const float* E,const float* S,const float* F,float* out0){
  int i = blockIdx.x*256 + threadIdx.x;
  int b=i/NPIX, n=i%NPIX;
  float v = lab[b*3*NPIX+n] - F[F_BETA+b*2]*E[i] - F[F_BETA+b*2+1]*S[i];
  out0[i] = v;
  unsigned u = f2u(v);
  unsigned mn=u, mx=u;
#pragma unroll
  for(int o=32;o;o>>=1){
    unsigned a = __shfl_down(mn,o,64); mn = (a<mn)?a:mn;
    unsigned c = __shfl_down(mx,o,64); mx = (c>mx)?c:mx;
  }
  __shared__ unsigned rmn[4], rmx[4];
  int wave=threadIdx.x>>6, lane=threadIdx.x&63;
  if(lane==0){ rmn[wave]=mn; rmx[wave]=mx; }
  __syncthreads();
  if(threadIdx.x==0){
    unsigned m0 = rmn[0]; unsigned m1 = rmx[0];
    for(int w=1;w<4;w++){ if(rmn[w]<m0)m0=rmn[w]; if(rmx[w]>m1)m1=rmx[w]; }
    unsigned* U = (unsigned*)F;
    int slot = blockIdx.x & 31;
    atomicMin(&U[F_MMS_MIN+b*32+slot], m0);
    atomicMax(&U[F_MMS_MAX+b*32+slot], m1);
  }
}

__global__ void k_xz_red(const float* Lp,const float* E,const float* S,float* F,double* A,
                         unsigned* T){
  int b = blockIdx.x / RB, blk = blockIdx.x % RB;
  const float* M = F + F_X3 + b*6;
  double s[9]={0,0,0,0,0,0,0,0,0};
  for(int n = blk*256 + threadIdx.x; n < NPIX; n += RB*256){
    float z0=(Lp[b*NPIX+n]-M[0])/M[1];
    float z1=(E [b*NPIX+n]-M[2])/M[3];
    float z2=(S [b*NPIX+n]-M[4])/M[5];
    s[0]+=z0; s[1]+=z1; s[2]+=z2;
    s[3]+=(double)z0*z0; s[4]+=(double)z0*z1; s[5]+=(double)z0*z2;
    s[6]+=(double)z1*z1; s[7]+=(double)z1*z2; s[8]+=(double)z2*z2;
  }
  __shared__ double red[4][9];
  int wave=threadIdx.x>>6, lane=threadIdx.x&63;
#pragma unroll
  for(int q=0;q<9;q++){
    s[q]=waveSum(s[q]);
    if(lane==0) red[wave][q]=s[q];
  }
  __syncthreads();
  if(threadIdx.x<9){
    double v = red[0][threadIdx.x]+red[1][threadIdx.x]+red[2][threadIdx.x]+red[3][threadIdx.x];
    atomicAdd(&A[A_XZ+b*9+threadIdx.x], v);
  }
  __shared__ int s_last;
  __syncthreads();
  if(threadIdx.x==0){
    __threadfence();
    s_last = (atomicAdd(&T[1],1u) == (unsigned)(NB*RB-1));
  }
  __syncthreads();
  if(!s_last) return;
  int bb = threadIdx.x;
  if(bb>=NB) return;
  const double* ss = A + A_XZ + bb*9;
  double inv = 1.0/(double)NPIX;
  double m0=ss[0]*inv, m1=ss[1]*inv, m2=ss[2]*inv;
  double a[3][3];
  a[0][0]=fmax(ss[3]*inv-m0*m0,1e-8);
  a[0][1]=a[1][0]=fmax(ss[4]*inv-m0*m1,1e-8);
  a[0][2]=a[2][0]=fmax(ss[5]*inv-m0*m2,1e-8);
  a[1][1]=fmax(ss[6]*inv-m1*m1,1e-8);
  a[1][2]=a[2][1]=fmax(ss[7]*inv-m1*m2,1e-8);
  a[2][2]=fmax(ss[8]*inv-m2*m2,1e-8);
  double V[3][3]={{1,0,0},{0,1,0},{0,0,1}};
  for(int sweep=0;sweep<40;sweep++){
    for(int pp=0;pp<3;pp++){
      int p = (pp==2)?1:0;
      int q = (pp==0)?1:2;
      double apq=a[p][q];
      if(fabs(apq)<1e-30) continue;
      double theta=(a[q][q]-a[p][p])/(2.0*apq);
      double t=((theta>=0)?1.0:-1.0)/(fabs(theta)+sqrt(1.0+theta*theta));
      double c=1.0/sqrt(1.0+t*t), sn=t*c;
      for(int k2=0;k2<3;k2++){ double akp=a[k2][p],akq=a[k2][q];
        a[k2][p]=c*akp-sn*akq; a[k2][q]=sn*akp+c*akq; }
      for(int k2=0;k2<3;k2++){ double apk=a[p][k2],aqk=a[q][k2];
        a[p][k2]=c*apk-sn*aqk; a[q][k2]=sn*apk+c*aqk; }
      for(int k2=0;k2<3;k2++){ double vkp=V[k2][p],vkq=V[k2][q];
        V[k2][p]=c*vkp-sn*vkq; V[k2][q]=sn*vkp+c*vkq; }
    }
  }
  double is0=1.0/sqrt(a[0][0]), is1=1.0/sqrt(a[1][1]), is2=1.0/sqrt(a[2][2]);
  for(int i=0;i<3;i++) for(int j=0;j<3;j++){
    double w = V[i][0]*is0*V[j][0] + V[i][1]*is1*V[j][1] + V[i][2]*is2*V[j][2];
    F[F_WWH + bb*9 + i*3 + j] = (float)w;
  }
  F[F_MEAN+bb*3]=(float)m0; F[F_MEAN+bb*3+1]=(float)m1; F[F_MEAN+bb*3+2]=(float)m2;
}

__global__ void k_xw(const float* Lp,const float* E,const float* S,const float* F,
                     float* Xw,int* idxP){
  __shared__ float s_mn, s_mx;
  int i = blockIdx.x*256 + threadIdx.x;
  int b=i/NPIX;
  if(threadIdx.x==0){
    const unsigned* U = (const unsigned*)F;
    unsigned mn=0xFFFFFFFFu, mx=0u;
    for(int s2=0;s2<32;s2++){
      unsigned a=U[F_MMS_MIN+b*32+s2]; if(a<mn)mn=a;
      unsigned c=U[F_MMS_MAX+b*32+s2]; if(c>mx)mx=c;
    }
    s_mn=u2f(mn); s_mx=u2f(mx);
  }
  __syncthreads();
  const float* M = F + F_X3 + b*6;
  float lp = Lp[i];
  float z0=(lp-M[0])/M[1];
  float z1=(E [i]-M[2])/M[3];
  float z2=(S [i]-M[4])/M[5];
  float d0=z0-F[F_MEAN+b*3], d1=z1-F[F_MEAN+b*3+1], d2=z2-F[F_MEAN+b*3+2];
  const float* Wm = F + F_WWH + b*9;
  Xw[3*(size_t)i  ]=d0*Wm[0]+d1*Wm[3]+d2*Wm[6];
  Xw[3*(size_t)i+1]=d0*Wm[1]+d1*Wm[4]+d2*Wm[7];
  Xw[3*(size_t)i+2]=d0*Wm[2]+d1*Wm[5]+d2*Wm[8];
  float ln = (lp-s_mn)/(s_mx-s_mn+1e-8f);
  ln = fminf(fmaxf(ln,0.f),1.f);
  int id = (int)(ln*32.f);
  idxP[i] = id>31?31:(id<0?0:id);
}

__global__ __launch_bounds__(256) void k_kurt(const float* Xw, const float* arand,
                                              double* A, float* F, unsigned* T){
  int g = blockIdx.x;           // 512
  int b   = g / ((NT/KDG)*KSEG);
  int rem = g % ((NT/KDG)*KSEG);
  int dg  = rem / KSEG;
  int seg = rem % KSEG;
  float a0[KDG],a1[KDG],a2[KDG];
#pragma unroll
  for(int j=0;j<KDG;j++){
    const float* ar = arand + (b*NT+dg*KDG+j)*3;
    float q0=ar[0],q1=ar[1],q2=ar[2];
    float nrm=(float)(sqrt((double)q0*q0+(double)q1*q1+(double)q2*q2)+1e-12);
    a0[j]=q0/nrm; a1[j]=q1/nrm; a2[j]=q2/nrm;
  }
  const float* X = Xw + (size_t)b*NPIX*3;
  double s[KDG][4];
#pragma unroll
  for(int j=0;j<KDG;j++){ s[j][0]=0; s[j][1]=0; s[j][2]=0; s[j][3]=0; }
  const int cnt = NPIX/KSEG;
  int start = seg*cnt;
  for(int n=start+threadIdx.x; n<start+cnt; n+=256){
    const float* p = X + 3*(size_t)n;
    float x=p[0], y=p[1], z=p[2];
#pragma unroll
    for(int j=0;j<KDG;j++){
      float zz = fmaf(x,a0[j],fmaf(y,a1[j], z*a2[j]));
      float z2f = zz*zz;
      s[j][0]+=zz; s[j][1]+=z2f; s[j][2]+=z2f*zz; s[j][3]+=(double)z2f*z2f;
    }
  }
  __shared__ double red[4][KDG*4];
  int wave=threadIdx.x>>6, lane=threadIdx.x&63;
#pragma unroll
  for(int j=0;j<KDG;j++)
#pragma unroll
    for(int m=0;m<4;m++){
      double v=waveSum(s[j][m]);
      if(lane==0) red[wave][j*4+m]=v;
    }
  __syncthreads();
  if(threadIdx.x<KDG*4){
    double v = red[0][threadIdx.x]+red[1][threadIdx.x]+red[2][threadIdx.x]+red[3][threadIdx.x];
    int j=threadIdx.x>>2, m=threadIdx.x&3;
    atomicAdd(&A[A_KURT + (size_t)(b*NT+dg*KDG+j)*4 + m], v);
  }
  __shared__ int s_last;
  __syncthreads();
  if(threadIdx.x==0){
    __threadfence();
    s_last = (atomicAdd(&T[5],1u) == (unsigned)(NB*(NT/KDG)*KSEG-1));
  }
  __syncthreads();
  if(!s_last) return;
  __shared__ float ak[NB*NT];
  {
    int tid=threadIdx.x;
    const double* K = A + A_KURT + (size_t)tid*4;
    double inv=1.0/(double)NPIX;
    double mean=K[0]*inv, M2=K[1]*inv, M3=K[2]*inv, M4=K[3]*inv;
    double m2 = M2 - mean*mean + 1e-12;
    double m4 = M4 - 4.0*mean*M3 + 6.0*mean*mean*M2 - 3.0*mean*mean*mean*mean;
    ak[tid] = (float)fabs(m4/(m2*m2) - 3.0);
  }
  __syncthreads();
  if(threadIdx.x<NB){
    int bb=threadIdx.x;
    int best=0; float bv=ak[bb*NT];
    for(int j=1;j<NT;j++){ float v=ak[bb*NT+j]; if(v>bv){bv=v;best=j;} }
    const float* ar = arand + (bb*NT+best)*3;
    double nrm = sqrt((double)ar[0]*ar[0]+(double)ar[1]*ar[1]+(double)ar[2]*ar[2])+1e-12;
    F[F_ASTAR+bb*3]  =(float)(ar[0]/nrm);
    F[F_ASTAR+bb*3+1]=(float)(ar[1]/nrm);
    F[F_ASTAR+bb*3+2]=(float)(ar[2]/nrm);
  }
}

__global__ void k_zbest(const float* Xw,const float* F,float* zb,double* A){
  int i = blockIdx.x*256 + threadIdx.x;
  int b=i/NPIX;
  const float* p = Xw + 3*(size_t)i;
  float v = p[0]*F[F_ASTAR+b*3] + p[1]*F[F_ASTAR+b*3+1] + p[2]*F[F_ASTAR+b*3+2];
  zb[i]=v;
  double s0=waveSum((double)v), s1=waveSum((double)v*v);
  __shared__ double red[4][2];
  int wave=threadIdx.x>>6, lane=threadIdx.x&63;
  if(lane==0){ red[wave][0]=s0; red[wave][1]=s1; }
  __syncthreads();
  if(threadIdx.x<2){
    double v2 = red[0][threadIdx.x]+red[1][threadIdx.x]+red[2][threadIdx.x]+red[3][threadIdx.x];
    atomicAdd(&A[A_ZTOT+b*2+threadIdx.x], v2);
  }
}

__global__ __launch_bounds__(256) void k_gmm_red(const float* zb, const float* F, double* A, int it){
  __shared__ float Q[3];
  __shared__ double red[4][3];
  int b = blockIdx.x / RB2, blk = blockIdx.x % RB2;
  if(threadIdx.x==0){
    float qa,qb,qc;
    if(it==0) quad_init(F,b,qa,qb,qc);
    else {
      const double* g = A + A_GMM + (it-1)*8 + b*4;
      quad_from_stats(g[0],g[1],g[2],A[A_ZTOT+b*2],A[A_ZTOT+b*2+1],qa,qb,qc);
    }
    Q[0]=qa;Q[1]=qb;Q[2]=qc;
  }
  __syncthreads();
  float qa=Q[0],qb=Q[1],qc=Q[2];
  double s0=0,s1=0,s2=0;
  for(int n = blk*256 + threadIdx.x; n < NPIX; n += RB2*256){
    float x = zb[b*NPIX+n];
    float f = fmaf(fmaf(qa,x,qb),x,qc);
    float r0 = 1.f/(1.f+expf(f));
    float rx = r0*x;
    s0+=r0; s1+=rx; s2+=(double)rx*x;
  }
  int wave=threadIdx.x>>6, lane=threadIdx.x&63;
  s0=waveSum(s0); s1=waveSum(s1); s2=waveSum(s2);
  if(lane==0){ red[wave][0]=s0; red[wave][1]=s1; red[wave][2]=s2; }
  __syncthreads();
  if(threadIdx.x<3){
    double v = red[0][threadIdx.x]+red[1][threadIdx.x]+red[2][threadIdx.x]+red[3][threadIdx.x];
    atomicAdd(&A[A_GMM+it*8+b*4+threadIdx.x], v);
  }
}

__global__ void k_ralpha(const float* zb, float* F, double* A, const int* idxP,
                         float* Ra0, float* Ra1, unsigned* T){
  __shared__ float h0[NBINS], h1[NBINS];
  __shared__ float Q[3];
  if(threadIdx.x<NBINS){ h0[threadIdx.x]=0.f; h1[threadIdx.x]=0.f; }
  int i = blockIdx.x*256 + threadIdx.x;
  int b=i/NPIX;
  if(threadIdx.x==0){
    const double* g = A + A_GMM + 8*8 + b*4;
    float qa,qb,qc;
    quad_from_stats(g[0],g[1],g[2],A[A_ZTOT+b*2],A[A_ZTOT+b*2+1],qa,qb,qc);
    Q[0]=qa;Q[1]=qb;Q[2]=qc;
  }
  __syncthreads();
  float x = zb[i];
  float f = fmaf(fmaf(Q[0],x,Q[1]),x,Q[2]);
  float r0 = 1.f/(1.f+expf(f));
  float r1 = 1.f-r0;
  float ra0=powf(r0,0.9f), ra1=powf(r1,0.9f);
  float s=ra0+ra1+1e-8f;
  ra0/=s; ra1/=s;
  Ra0[i]=ra0; Ra1[i]=ra1;
  int id = idxP[i];
  atomicAdd(&h0[id], ra0);
  atomicAdd(&h1[id], ra1);
  __syncthreads();
  if(threadIdx.x<NBINS){
    if(h0[threadIdx.x]!=0.f) atomicAdd(&A[A_GHIST+(0*NB+b)*32+threadIdx.x], (double)h0[threadIdx.x]);
    if(h1[threadIdx.x]!=0.f) atomicAdd(&A[A_GHIST+(1*NB+b)*32+threadIdx.x], (double)h1[threadIdx.x]);
  }
  __shared__ int s_last;
  __syncthreads();
  if(threadIdx.x==0){
    __threadfence();
    s_last = (atomicAdd(&T[2],1u) == (unsigned)(BN/256-1));
  }
  __syncthreads();
  if(!s_last) return;
  int t = threadIdx.x;
  if(t>=4) return;
  const double* gh = A + A_GHIST + t*32;
  double sum=0;
  for(int j=0;j<NBINS;j++) sum += gh[j];
  double c=0;
  for(int j=0;j<NBINS;j++){
    c += gh[j]/(sum+1e-8);
    F[F_GCDF+t*32+j]=(float)c;
  }
}

__global__ void k_dk_red(const float* Lp,const float* E,const float* S,
                         const float* Ra0,const float* Ra1,double* A,float* F,unsigned* T){
  int b = blockIdx.x / RB, blk = blockIdx.x % RB;
  double s[20];
#pragma unroll
  for(int q=0;q<20;q++) s[q]=0;
  for(int n = blk*256 + threadIdx.x; n < NPIX; n += RB*256){
    int i=b*NPIX+n;
    double w0=Ra0[i], w1=Ra1[i];
    double x0=Lp[i], x1=E[i], x2=S[i];
    s[0]+=w0; s[1]+=w0*x0; s[2]+=w0*x1; s[3]+=w0*x2;
    s[4]+=w0*x0*x0; s[5]+=w0*x0*x1; s[6]+=w0*x0*x2; s[7]+=w0*x1*x1; s[8]+=w0*x1*x2; s[9]+=w0*x2*x2;
    s[10]+=w1; s[11]+=w1*x0; s[12]+=w1*x1; s[13]+=w1*x2;
    s[14]+=w1*x0*x0; s[15]+=w1*x0*x1; s[16]+=w1*x0*x2; s[17]+=w1*x1*x1; s[18]+=w1*x1*x2; s[19]+=w1*x2*x2;
  }
  __shared__ double red[4][20];
  int wave=threadIdx.x>>6, lane=threadIdx.x&63;
#pragma unroll
  for(int q=0;q<20;q++){
    s[q]=waveSum(s[q]);
    if(lane==0) red[wave][q]=s[q];
  }
  __syncthreads();
  if(threadIdx.x<20){
    double v = red[0][threadIdx.x]+red[1][threadIdx.x]+red[2][threadIdx.x]+red[3][threadIdx.x];
    atomicAdd(&A[A_DK+b*20+threadIdx.x], v);
  }
  __shared__ int s_last;
  __syncthreads();
  if(threadIdx.x==0){
    __threadfence();
    s_last = (atomicAdd(&T[3],1u) == (unsigned)(NB*RB-1));
  }
  __syncthreads();
  if(!s_last || threadIdx.x) return;
  for(int bb=0;bb<NB;bb++) for(int k=0;k<2;k++){
    const double* ss = A + A_DK + (bb*2+k)*10;
    double W0=ss[0], Ws=W0+1e-8;
    double mu0=ss[1]/Ws, mu1=ss[2]/Ws, mu2=ss[3]/Ws;
    double C00=(ss[4]-2.0*mu0*ss[1]+mu0*mu0*W0)/Ws + 1e-6;
    double C01=(ss[5]-mu0*ss[2]-mu1*ss[1]+mu0*mu1*W0)/Ws;
    double C02=(ss[6]-mu0*ss[3]-mu2*ss[1]+mu0*mu2*W0)/Ws;
    double C11=(ss[7]-2.0*mu1*ss[2]+mu1*mu1*W0)/Ws + 1e-6;
    double C12=(ss[8]-mu1*ss[3]-mu2*ss[2]+mu1*mu2*W0)/Ws;
    double C22=(ss[9]-2.0*mu2*ss[3]+mu2*mu2*W0)/Ws + 1e-6;
    double det = C00*(C11*C22-C12*C12) - C01*(C01*C22-C12*C02) + C02*(C01*C12-C11*C02);
    double id = 1.0/det;
    float* P = F + F_DKINV + (bb*2+k)*9;
    P[0]=(float)((C11*C22-C12*C12)*id);
    P[1]=(float)((C02*C12-C01*C22)*id);
    P[2]=(float)((C01*C12-C02*C11)*id);
    P[3]=(float)((C00*C22-C02*C02)*id);
    P[4]=(float)((C01*C02-C00*C12)*id);
    P[5]=(float)((C00*C11-C01*C01)*id);
    P[6]=(float)mu0; P[7]=(float)mu1; P[8]=(float)mu2;
  }
}

// LLA for both k in one launch
__global__ __launch_bounds__(256) void k_lla(const float* Ra0, const float* Ra1,
                                             const float* Lp, float* tmpL){
  int kk = blockIdx.x / (NB*576);
  int inner = blockIdx.x % (NB*576);
  int bx = inner % 24, by = (inner/24) % 24, b = inner/576;
  const float* rk = kk ? Ra1 : Ra0;
  __shared__ float Rt[30][31], Lt[30][31];
  __shared__ float h0[30][17], h1[30][17], h2[30][17];
  int ox = bx*16, oy = by*16;
  const float* Rb = rk + (size_t)b*NPIX;
  const float* Lb = Lp + (size_t)b*NPIX;
  for(int i=threadIdx.x; i<900; i+=256){
    int lx=i%30, ly=i/30;
    int gx_=ox-7+lx, gy_=oy-7+ly;
    bool in = (gx_>=0&&gx_<WW&&gy_>=0&&gy_<HH);
    Rt[ly][lx]= in ? Rb[gy_*WW+gx_] : 0.f;
    Lt[ly][lx]= in ? Lb[gy_*WW+gx_] : 0.f;
  }
  __syncthreads();
  for(int i=threadIdx.x; i<480; i+=256){
    int j=i%16, r=i/16;
    float s0=0,s1=0,s2=0;
#pragma unroll
    for(int d=0;d<15;d++){
      float rr=Rt[r][j+d], ll=Lt[r][j+d];
      s0+=rr; float rl=rr*ll; s1+=rl; s2+=rl*ll;
    }
    h0[r][j]=s0; h1[r][j]=s1; h2[r][j]=s2;
  }
  __syncthreads();
  int tx=threadIdx.x%16, ty=threadIdx.x/16;
  float S0=0,S1=0,S2=0;
#pragma unroll
  for(int d=0;d<15;d++){ S0+=h0[ty+d][tx]; S1+=h1[ty+d][tx]; S2+=h2[ty+d][tx]; }
  int x=ox+tx, y=oy+ty;
  float cy = (float)((y+8<HH?y+8:HH)-(y-7>0?y-7:0));
  float cx = (float)((x+8<WW?x+8:WW)-(x-7>0?x-7:0));
  float cnt = cy*cx;
  float den = S0/cnt + 1e-8f;
  float mu  = (S1/cnt)/den;
  float var = fmaxf((S2/cnt)/den - mu*mu, 1e-8f);
  int n = y*WW+x;
  tmpL[(size_t)kk*BN + b*NPIX+n] = fabsf(Lb[n]-mu)/(sqrtf(var)+1e-8f);
}

// GLD both k; sliding-window vertical in 16-bin halves
__global__ __launch_bounds__(256) void k_gldf(const float* Ra0, const float* Ra1,
                                              const int* idxP, const float* F, float* tmpG){
  int kk = blockIdx.x / (NB*576);
  int inner = blockIdx.x % (NB*576);
  int bx = inner % 24, by = (inner/24) % 24, b = inner/576;
  const float* rk = kk ? Ra1 : Ra0;
  __shared__ float Rt[30][31];
  __shared__ unsigned char It[30][32];
  __shared__ float Hh[16*GHS];
  __shared__ float Vv[16*GVS];
  __shared__ float gc[NBINS];
  if(threadIdx.x<NBINS) gc[threadIdx.x]=F[F_GCDF+(kk*NB+b)*32+threadIdx.x];
  int ox=bx*16, oy=by*16;
  const float* Rb = rk + (size_t)b*NPIX;
  const int* Ib = idxP + (size_t)b*NPIX;
  for(int i=threadIdx.x;i<900;i+=256){
    int lx=i%30, ly=i/30;
    int gx_=ox-7+lx, gy_=oy-7+ly;
    bool in = (gx_>=0&&gx_<WW&&gy_>=0&&gy_<HH);
    Rt[ly][lx] = in? Rb[gy_*WW+gx_] : 0.f;
    It[ly][lx] = in? (unsigned char)Ib[gy_*WW+gx_] : 0;
  }
  int tx=threadIdx.x%16, ty=threadIdx.x/16;
  float vs[32];
  for(int half=0; half<2; ++half){
    int base = half*16;
    __syncthreads();               // protect Hh/Vv reuse
    for(int i=threadIdx.x;i<16*GHS;i+=256) Hh[i]=0.f;
    __syncthreads();
    for(int i=threadIdx.x;i<480;i+=256){
      int j=i%16, r=i/16;
      for(int d=0;d<15;d++){
        int bin = (int)It[r][j+d];
        if((bin>>4)==half) Hh[(bin&15)*GHS + i] += Rt[r][j+d];
      }
    }
    __syncthreads();
    {
      int j  = threadIdx.x%16;
      int bn = threadIdx.x/16;
      const float* h = Hh + bn*GHS;
      float s=0;
#pragma unroll
      for(int r=0;r<15;r++) s += h[r*16+j];
      Vv[bn*GVS + 0*16 + j] = s;
      for(int yy=1;yy<16;yy++){
        s += h[(yy+14)*16+j] - h[(yy-1)*16+j];
        Vv[bn*GVS + yy*16 + j] = s;
      }
    }
    __syncthreads();
#pragma unroll
    for(int jb=0;jb<16;jb++) vs[base+jb] = Vv[jb*GVS + ty*16 + tx];
  }
  int x=ox+tx, y=oy+ty;
  float cy = (float)((y+8<HH?y+8:HH)-(y-7>0?y-7:0));
  float cx = (float)((x+8<WW?x+8:WW)-(x-7>0?x-7:0));
  float cnt = cy*cx;
  float tot=0;
#pragma unroll
  for(int bin=0;bin<NBINS;bin++) tot += vs[bin];
  float den = tot/cnt + 1e-8f;
  float cs=0, acc=0;
#pragma unroll
  for(int bin=0;bin<NBINS;bin++){
    cs += vs[bin];
    acc += fabsf((cs/cnt)/den - gc[bin]);
  }
  tmpG[(size_t)kk*BN + b*NPIX + y*WW + x] = acc*(1.f/32.f);
}

// fused DM + gamma + L_anom
__global__ void k_lanom(const float* Lp,const float* E,const float* S,
                        const float* tmpL,const float* tmpG,
                        const float* Ra0,const float* Ra1,
                        const float* F,float* La){
  int i = blockIdx.x*256 + threadIdx.x; if(i>=BN) return;
  int b=i/NPIX;
  float x0=Lp[i], x1=E[i], x2=S[i];
  float D[2];
#pragma unroll
  for(int k=0;k<2;k++){
    const float* P = F + F_DKINV + (b*2+k)*9;
    float d0=x0-P[6], d1=x1-P[7], d2=x2-P[8];
    float q = d0*d0*P[0] + d1*d1*P[3] + d2*d2*P[5]
            + 2.f*(d0*d1*P[1] + d0*d2*P[2] + d1*d2*P[4]);
    D[k]=sqrtf(q+1e-8f);
  }
  float ra0=Ra0[i], ra1=Ra1[i];
  float w0=ra0+1e-8f, w1=ra1+1e-8f;
  float DM = (w0*D[0]+w1*D[1])/(w0+w1);
  float g = 1.0f;
#pragma unroll
  for(int kk=0;kk<2;kk++){
    const float* ML = F + F_CM + (kk*4 + 0 + b)*2;
    const float* MG = F + F_CM + (kk*4 + 2 + b)*2;
    float zl=(tmpL[(size_t)kk*BN+i]-ML[0])/ML[1];
    float zg=(tmpG[(size_t)kk*BN+i]-MG[0])/MG[1];
    float rk = kk ? ra1 : ra0;
    g += rk*(0.5f*sp(zl)+0.5f*sp(zg));
  }
  const float* M = F + F_X3 + b*6;
  const float* P = F + F_ESI + b*5;
  float z0=(x1-M[2])/M[3];
  float z1=(x2-M[4])/M[5];
  float d0=z0-P[0], d1=z1-P[1];
  float d2 = d0*d0*P[2] + 2.f*d0*d1*P[3] + d1*d1*P[4];
  float Rs = expf(-0.5f*d2);
  La[i] = fmaxf(DM*g*(1.f-Rs), 0.f);
}

__global__ void k_es_red(const float* E,const float* S,float* F,double* A,unsigned* T){
  int b = blockIdx.x / RB, blk = blockIdx.x % RB;
  const float* M = F + F_X3 + b*6;
  double s[5]={0,0,0,0,0};
  for(int n = blk*256 + threadIdx.x; n < NPIX; n += RB*256){
    float z0=(E[b*NPIX+n]-M[2])/M[3];
    float z1=(S[b*NPIX+n]-M[4])/M[5];
    s[0]+=z0; s[1]+=z1; s[2]+=(double)z0*z0; s[3]+=(double)z0*z1; s[4]+=(double)z1*z1;
  }
  __shared__ double red[4][5];
  int wave=threadIdx.x>>6, lane=threadIdx.x&63;
#pragma unroll
  for(int q=0;q<5;q++){
    s[q]=waveSum(s[q]);
    if(lane==0) red[wave][q]=s[q];
  }
  __syncthreads();
  if(threadIdx.x<5){
    double v = red[0][threadIdx.x]+red[1][threadIdx.x]+red[2][threadIdx.x]+red[3][threadIdx.x];
    atomicAdd(&A[A_ES+b*5+threadIdx.x], v);
  }
  __shared__ int s_last;
  __syncthreads();
  if(threadIdx.x==0){
    __threadfence();
    s_last = (atomicAdd(&T[4],1u) == (unsigned)(NB*RB-1));
  }
  __syncthreads();
  if(!s_last || threadIdx.x) return;
  for(int bb=0;bb<NB;bb++){
    const double* ss = A + A_ES + bb*5;
    double inv=1.0/(double)NPIX;
    double m0=ss[0]*inv, m1=ss[1]*inv;
    double c00=ss[2]*inv - m0*m0 + 1e-6;
    double c01=ss[3]*inv - m0*m1;
    double c11=ss[4]*inv - m1*m1 + 1e-6;
    double det=c00*c11-c01*c01;
    float* P = F + F_ESI + bb*5;
    P[0]=(float)m0; P[1]=(float)m1;
    P[2]=(float)(c11/det); P[3]=(float)(-c01/det); P[4]=(float)(c00/det);
  }
}
__global__ void k_out2(const float* La, const float* F, float* out){
  int i = blockIdx.x*256 + threadIdx.x; if(i>=BN) return;
  int b=i/NPIX;
  const float* v = F + F_LAQ + b*4;
  double h1 = 0.01*(double)(NPIX-1); double f1 = h1 - floor(h1);
  double h9 = 0.99*(double)(NPIX-1); double f9 = h9 - floor(h9);
  float q1 = (float)((double)v[0] + f1*((double)v[1]-(double)v[0]));
  float q9 = (float)((double)v[2] + f9*((double)v[3]-(double)v[2]));
  float r = (La[i]-q1)/(q9-q1+1e-8f);
  out[BN + i] = fminf(fmaxf(r,0.f),1.f);
}

// ---------------- host ----------------
static void run_sel(const SelBatch& sb, unsigned* H, unsigned* T, float* F, int bid, hipStream_t s){
  for(int p=2;p>=0;--p) k_selp<<<sb.nt*SEL_BLK,256,0,s>>>(sb,H,T,F,bid,0,p);
  if(sb.medmad) for(int p=2;p>=0;--p) k_selp<<<sb.nt*SEL_BLK,256,0,s>>>(sb,H,T,F,bid,1,p);
}

extern "C" void kernel_launch(void* const* d_in, const int* in_sizes, int n_in,
                              void* d_out, int out_size, void* d_ws, size_t ws_size,
                              hipStream_t stream){
  (void)in_sizes; (void)n_in; (void)out_size; (void)ws_size;
  const float* lab   = (const float*)d_in[0];
  const float* arand = (const float*)d_in[1];
  float* out = (float*)d_out;
  char* wsb = (char*)d_ws;
  double* A = (double*)wsb;
  float*  F = (float*)(wsb + 16384);
  unsigned* T = (unsigned*)(wsb + 32768);
  unsigned* H = (unsigned*)(wsb + 65536);
  float* planes = (float*)(wsb + (size_t)4*1024*1024);
  float* E    = planes;
  float* S    = planes + (size_t)BN;
  float* tA   = planes + (size_t)2*BN;        // La
  float* tmpL = planes + (size_t)3*BN;        // 2 planes
  float* tmpG = planes + (size_t)5*BN;        // 2 planes
  float* Xw   = planes + (size_t)7*BN;        // 3 planes
  float* zb   = planes + (size_t)10*BN;
  float* Ra0  = planes + (size_t)11*BN;
  float* Ra1  = planes + (size_t)12*BN;
  int*   idxP = (int*)(planes + (size_t)16*BN);

  const int GBN = BN/256;      // 1152

  k_zero<<<256,256,0,stream>>>(A,F,T,H);
  k_sobel<<<NB*576,256,0,stream>>>(lab,S,E);
  k_beta_red<<<NB*RB,256,0,stream>>>(E,S,lab,A,F,T);
  k_lperp<<<GBN,256,0,stream>>>(lab,E,S,F,out);

  SelBatch sbX; sbX.nt=6; sbX.medmad=1;
  for(int b=0;b<NB;b++){
    sbX.src[b*3+0]=out+(size_t)b*NPIX; sbX.src[b*3+1]=E+(size_t)b*NPIX; sbX.src[b*3+2]=S+(size_t)b*NPIX;
    for(int ch=0;ch<3;ch++){ sbX.rank[b*3+ch]=MEDRANK; sbX.fslot[b*3+ch]=F_X3+(b*3+ch)*2; }
  }
  run_sel(sbX,H,T,F,0,stream);

  k_xz_red<<<NB*RB,256,0,stream>>>(out,E,S,F,A,T);
  k_es_red<<<NB*RB,256,0,stream>>>(E,S,F,A,T);
  k_xw<<<GBN,256,0,stream>>>(out,E,S,F,Xw,idxP);
  k_kurt<<<NB*(NT/KDG)*KSEG,256,0,stream>>>(Xw,arand,A,F,T);
  k_zbest<<<GBN,256,0,stream>>>(Xw,F,zb,A);

  SelBatch sbZ; sbZ.nt=8; sbZ.medmad=0;
  {
    int rr[4]={36863,36864,110591,110592};
    for(int b=0;b<NB;b++) for(int ri=0;ri<4;ri++){
      int t=b*4+ri;
      sbZ.src[t]=zb+(size_t)b*NPIX; sbZ.rank[t]=rr[ri]; sbZ.fslot[t]=F_ZBQ+b*4+ri;
    }
  }
  run_sel(sbZ,H,T,F,1,stream);

  for(int it=0; it<9; ++it)
    k_gmm_red<<<NB*RB2,256,0,stream>>>(zb,F,A,it);
  k_ralpha<<<GBN,256,0,stream>>>(zb,F,A,idxP,Ra0,Ra1,T);
  k_dk_red<<<NB*RB,256,0,stream>>>(out,E,S,Ra0,Ra1,A,F,T);

  k_lla<<<2*NB*576,256,0,stream>>>(Ra0,Ra1,out,tmpL);
  k_gldf<<<2*NB*576,256,0,stream>>>(Ra0,Ra1,idxP,F,tmpG);

  SelBatch sbC; sbC.nt=8; sbC.medmad=1;
  for(int kk=0;kk<2;kk++) for(int isG=0;isG<2;isG++) for(int b=0;b<NB;b++){
    int t = kk*4 + isG*2 + b;
    sbC.src[t] = (isG? tmpG: tmpL) + (size_t)kk*BN + (size_t)b*NPIX;
    sbC.rank[t]=MEDRANK; sbC.fslot[t]=F_CM + t*2;
  }
  run_sel(sbC,H,T,F,2,stream);

  k_lanom<<<GBN,256,0,stream>>>(out,E,S,tmpL,tmpG,Ra0,Ra1,F,tA);

  SelBatch sbL; sbL.nt=8; sbL.medmad=0;
  {
    int rr[4]={1474,1475,145980,145981};
    for(int b=0;b<NB;b++) for(int ri=0;ri<4;ri++){
      int t=b*4+ri;
      sbL.src[t]=tA+(size_t)b*NPIX; sbL.rank[t]=rr[ri]; sbL.fslot[t]=F_LAQ+b*4+ri;
    }
  }
  run_sel(sbL,H,T,F,3,stream);

  k_out2<<<GBN,256,0,stream>>>(tA,F,out);
}